// Round 21
// baseline (159.470 us; speedup 1.0000x reference)
//
#include <hip/hip_runtime.h>

typedef __bf16 bf16;
typedef __attribute__((ext_vector_type(8))) __bf16 bf16x8;
typedef __attribute__((ext_vector_type(4))) __bf16 bf16x4;
typedef __attribute__((ext_vector_type(4))) float f32x4;
typedef unsigned long long u64;

static constexpr int S = 2048, B = 2, H = 1024, NH = 16, HD = 64;
static constexpr int ROWS = S * B;        // 4096 GEMM rows (s*B+b)
static constexpr int NQKV = 3 * NH * HD;  // 3072
static constexpr int KBLK = 64;
static constexpr int NT = S / KBLK;       // 32 k-tiles (attn)
static constexpr int MW = S / 64;         // mask u64 words per row
static constexpr float LOG2E = 1.4426950408889634f;
static constexpr int G0_WG = (NQKV / 128) * (ROWS / 128);  // 768 gemm0 work blocks
static constexpr int PACK_WG = (B * S * S) / (256 * 16);   // 2048 pack blocks

__device__ __forceinline__ int swz(int row, int col) { return col ^ ((row & 7) << 3); }

__device__ __forceinline__ void g2l16(const bf16* g, bf16* l) {
  __builtin_amdgcn_global_load_lds((const __attribute__((address_space(1))) void*)g,
                                   (__attribute__((address_space(3))) void*)l, 16, 0, 0);
}

// ---------- prep: weight transpose+cvt (LOG2E in Q cols) + LayerNorm + mask pack ----------
__global__ __launch_bounds__(256) void prep_kernel(const float* __restrict__ wqkv,
                                                   const float* __restrict__ wout,
                                                   bf16* __restrict__ dqkv,
                                                   bf16* __restrict__ dout,
                                                   const float* __restrict__ x,
                                                   const float* __restrict__ sc,
                                                   const float* __restrict__ bi,
                                                   bf16* __restrict__ lnout,
                                                   const void* __restrict__ mask,
                                                   u64* __restrict__ bits) {
  __shared__ float shmem[32 * 33];
  const int bid = blockIdx.x;
  const int tid = threadIdx.x;
  if (bid < 4096) {
    const int bx = bid & 127, by = bid >> 7;
    const bool second = bx >= (NQKV / 32);
    const float* src = second ? wout : wqkv;
    bf16* dst = second ? dout : dqkv;
    const int C = second ? H : NQKV;
    const int c0 = (second ? bx - NQKV / 32 : bx) * 32, r0 = by * 32;
    const int xx = tid & 31, yy = tid >> 5;
#pragma unroll
    for (int i = 0; i < 32; i += 8)
      shmem[(yy + i) * 33 + xx] = src[(size_t)(r0 + yy + i) * C + c0 + xx];
    __syncthreads();
#pragma unroll
    for (int i = 0; i < 32; i += 8) {
      const int col = c0 + yy + i;
      const float scale = (!second && col < 1024) ? LOG2E : 1.0f;
      dst[(size_t)col * H + r0 + xx] = (bf16)(shmem[xx * 33 + yy + i] * scale);
    }
  } else if (bid < 8192) {
    const int row = bid - 4096;
    const float4 v = *(const float4*)&x[(size_t)row * H + tid * 4];
    float s = v.x + v.y + v.z + v.w;
#pragma unroll
    for (int m = 1; m < 64; m <<= 1) s += __shfl_xor(s, m);
    float* red1 = shmem;
    float* red2 = shmem + 8;
    const int w = tid >> 6, lane = tid & 63;
    if (lane == 0) red1[w] = s;
    __syncthreads();
    const float mean = (red1[0] + red1[1] + red1[2] + red1[3]) * (1.0f / H);
    const float dx = v.x - mean, dy = v.y - mean, dz = v.z - mean, dw = v.w - mean;
    float q = dx * dx + dy * dy + dz * dz + dw * dw;
#pragma unroll
    for (int m = 1; m < 64; m <<= 1) q += __shfl_xor(q, m);
    if (lane == 0) red2[w] = q;
    __syncthreads();
    const float var = (red2[0] + red2[1] + red2[2] + red2[3]) * (1.0f / H);
    const float inv = rsqrtf(var + 1e-6f);
    const float4 s4 = *(const float4*)&sc[tid * 4];
    const float4 b4 = *(const float4*)&bi[tid * 4];
    bf16x4 o;
    o[0] = (bf16)(dx * inv * s4.x + b4.x);
    o[1] = (bf16)(dy * inv * s4.y + b4.y);
    o[2] = (bf16)(dz * inv * s4.z + b4.z);
    o[3] = (bf16)(dw * inv * s4.w + b4.w);
    *(bf16x4*)&lnout[(size_t)row * H + tid * 4] = o;
  } else {
    // ---- mask pack, 4096 elements per block; dtype detected from OWN 4KB byte window ----
    const int p = bid - 8192;
    const size_t base = (size_t)p * 4096;
    int* det = (int*)shmem;
    if (tid == 0) det[0] = 0;
    __syncthreads();
    const uint4 wv = *(const uint4*)((const unsigned char*)mask + base + (size_t)tid * 16);
    const unsigned any3 = (wv.x | wv.y | wv.z | wv.w) & 0xFFFFFF00u;
    if (any3) atomicOr(det, 1);
    __syncthreads();
    const bool imode = (det[0] == 0);
#pragma unroll
    for (int k = 0; k < 16; ++k) {
      const size_t e = base + k * 256 + tid;
      int mv;
      if (imode) mv = ((const int*)mask)[e];
      else mv = (int)((const unsigned char*)mask)[e];
      const u64 bal = __ballot(mv != 0);
      if ((tid & 63) == 0) bits[e >> 6] = bal;
    }
  }
}

// ---------- 128x128 bf16 MFMA GEMM, BK=32 (32KB LDS -> 4 blocks/CU), dbuf + counted vmcnt ----------
// 64B LDS rows: fragment col = (g*8) ^ (((l15>>1)&3)<<3); source col = 8*((lane&3)^((lane>>3)&3)).
template <int EPI>
__global__ __launch_bounds__(256) void gemm128(const bf16* __restrict__ A, const bf16* __restrict__ Bt,
                                               bf16* __restrict__ qo, bf16* __restrict__ ko,
                                               bf16* __restrict__ vo, float* __restrict__ out) {
  constexpr int K = 1024;
  constexpr int NKT = K / 32;  // 32 K-tiles of 32
  __shared__ __align__(16) bf16 As[2][128][32];
  __shared__ __align__(16) bf16 Bs[2][128][32];
  int lin, NX, total;
  if (EPI == 0) {
    lin = blockIdx.x;
    NX = NQKV / 128; total = G0_WG;
  } else {
    lin = blockIdx.y * gridDim.x + blockIdx.x;
    NX = gridDim.x; total = gridDim.x * gridDim.y;
  }
  const int cpx = total >> 3;
  const int work = (lin & 7) * cpx + (lin >> 3);
  const int bm = (work / NX) * 128, bn = (work % NX) * 128;
  const bool isV = (EPI == 0) && (bn >= 2048);
  const int tid = threadIdx.x;
  const int wave = tid >> 6, lane = tid & 63;
  const int wm = (wave >> 1) * 64, wn = (wave & 1) * 64;
  const int g = lane >> 4, l15 = lane & 15;
  const int lr = lane >> 2;                                // row within 16-row group
  const int lc = 8 * ((lane & 3) ^ ((lane >> 3) & 3));     // pre-swizzled source col
  const int fcx = ((l15 >> 1) & 3) << 3;                   // fragment-read XOR
  const bf16* Ab = &A[(size_t)bm * K];
  const bf16* Bb = &Bt[(size_t)bn * K];

  f32x4 acc[4][4] = {};
  // prologue: issue prefetch of tile 0 into buf 0 (4 loads/thread total)
#pragma unroll
  for (int p = 0; p < 2; ++p) {
    const int r0 = wave * 16 + p * 64;
    g2l16(&Ab[(size_t)(r0 + lr) * K + lc], &As[0][r0][0]);
    g2l16(&Bb[(size_t)(r0 + lr) * K + lc], &Bs[0][r0][0]);
  }

  for (int kt = 0; kt < NKT; ++kt) {
    const int cur = kt & 1;
    if (kt + 1 < NKT) {
      const int ko2 = (kt + 1) * 32;
#pragma unroll
      for (int p = 0; p < 2; ++p) {
        const int r0 = wave * 16 + p * 64;
        g2l16(&Ab[(size_t)(r0 + lr) * K + ko2 + lc], &As[cur ^ 1][r0][0]);
        g2l16(&Bb[(size_t)(r0 + lr) * K + ko2 + lc], &Bs[cur ^ 1][r0][0]);
      }
      asm volatile("s_waitcnt vmcnt(4)" ::: "memory");  // tile-kt fill done; kt+1 in flight
    } else {
      asm volatile("s_waitcnt vmcnt(0)" ::: "memory");
    }
    __builtin_amdgcn_sched_barrier(0);
    __builtin_amdgcn_s_barrier();
    __builtin_amdgcn_sched_barrier(0);
    {
      bf16x8 af[4], bb[4];
#pragma unroll
      for (int i = 0; i < 4; ++i) af[i] = *(const bf16x8*)&As[cur][wm + i * 16 + l15][(g * 8) ^ fcx];
#pragma unroll
      for (int j = 0; j < 4; ++j) bb[j] = *(const bf16x8*)&Bs[cur][wn + j * 16 + l15][(g * 8) ^ fcx];
      __builtin_amdgcn_s_setprio(1);
      if (isV) {
#pragma unroll
        for (int i = 0; i < 4; ++i)
#pragma unroll
          for (int j = 0; j < 4; ++j)
            acc[i][j] = __builtin_amdgcn_mfma_f32_16x16x32_bf16(bb[j], af[i], acc[i][j], 0, 0, 0);
      } else {
#pragma unroll
        for (int i = 0; i < 4; ++i)
#pragma unroll
          for (int j = 0; j < 4; ++j)
            acc[i][j] = __builtin_amdgcn_mfma_f32_16x16x32_bf16(af[i], bb[j], acc[i][j], 0, 0, 0);
      }
      __builtin_amdgcn_s_setprio(0);
    }
    __builtin_amdgcn_sched_barrier(0);
    asm volatile("s_waitcnt lgkmcnt(0)" ::: "memory");
    __builtin_amdgcn_sched_barrier(0);
    __builtin_amdgcn_s_barrier();
    __builtin_amdgcn_sched_barrier(0);
  }
#pragma unroll
  for (int i = 0; i < 4; ++i) {
#pragma unroll
    for (int j = 0; j < 4; ++j) {
#pragma unroll
      for (int r = 0; r < 4; ++r) {
        const float val = acc[i][j][r];
        if (isV) {
          const int row = bm + wm + i * 16 + l15;
          const int col = bn + wn + j * 16 + g * 4 + r;
          const int f = col & 1023;
          const int h = f >> 6, d = f & 63;
          const int sdx = row >> 1, b = row & 1;
          vo[(((size_t)b * NH + h) * HD + d) * S + sdx] = (bf16)val;
        } else if (EPI == 0) {
          const int row = bm + wm + i * 16 + g * 4 + r;
          const int col = bn + wn + j * 16 + l15;
          const int kk = col >> 10, f = col & 1023;
          const int h = f >> 6, d = f & 63;
          const int sdx = row >> 1, b = row & 1;
          const size_t head = (size_t)b * NH + h;
          if (kk == 0)
            qo[(head * S + sdx) * HD + d] = (bf16)val;
          else
            ko[(head * S + sdx) * HD + d] = (bf16)val;
        } else {
          const int row = bm + wm + i * 16 + g * 4 + r;
          const int col = bn + wn + j * 16 + l15;
          out[(size_t)row * H + col] = val;
        }
      }
    }
  }
}

// ---------- flash attention: 8 waves x 16 q-rows (128/block), grid 512, swapped QK^T (R15) ----------
__global__ __launch_bounds__(512, 4) void attn_kernel(const bf16* __restrict__ Qb, const bf16* __restrict__ Kb,
                                                      const bf16* __restrict__ Vt, const u64* __restrict__ mbits,
                                                      bf16* __restrict__ ctx) {
  __shared__ __align__(16) bf16 Ks[2][64][64];
  __shared__ __align__(16) bf16 Vs[2][64][64];
  __shared__ __align__(16) bf16 P[8][16][64];
  // XCD-chunked swizzle: 512 blocks -> each XCD gets 64 consecutive works (4 heads)
  const int lin = blockIdx.y * 16 + blockIdx.x;
  const int work = ((lin & 7) << 6) | (lin >> 3);
  const int bh = work >> 4, qb = work & 15;
  const int b = bh >> 4, h = bh & 15;
  const int tid = threadIdx.x, w = tid >> 6, lane = tid & 63;
  const int g = lane >> 4, c = lane & 15;
  const int q0 = qb * 128 + w * 16;
  const size_t head = (size_t)b * NH + h;
  const bf16* Qh = Qb + head * S * HD;
  const bf16* Kh = Kb + head * S * HD;
  const bf16* Vh = Vt + head * HD * S;

  // staging: wave w stages rows [w*8, w*8+8); LDS linear, swizzle on global source col
  const int srow = w * 8 + (lane >> 3);
  const int scol = 8 * ((lane & 7) ^ (lane >> 3));

  bf16x8 aq[2];
#pragma unroll
  for (int ks = 0; ks < 2; ++ks)
    aq[ks] = *(const bf16x8*)&Qh[(size_t)(q0 + c) * HD + ks * 32 + g * 8];

  f32x4 o[4] = {};
  float lsum = 0.f;  // lane-local partial; cross-lane reduction deferred to epilogue

  // prologue: stage tile 0 into buf0
  g2l16(&Kh[(size_t)srow * HD + scol], &Ks[0][w * 8][0]);
  g2l16(&Vh[(size_t)srow * S + scol], &Vs[0][w * 8][0]);
  __syncthreads();

  for (int t = 0; t < NT; ++t) {
    const int cur = t & 1;
    if (t + 1 < NT) {  // async staging for tile t+1 (drained at end-of-iter barrier)
      const int kt1 = (t + 1) * KBLK;
      g2l16(&Kh[(size_t)(kt1 + srow) * HD + scol], &Ks[cur ^ 1][w * 8][0]);
      g2l16(&Vh[(size_t)srow * S + kt1 + scol], &Vs[cur ^ 1][w * 8][0]);
    }
    // ---- QK^T swapped: sv[j][r] = log2e * S[q=q0+c][k=kt+j*16+g*4+r] ----
    f32x4 sv[4] = {};
#pragma unroll
    for (int ks = 0; ks < 2; ++ks) {
      bf16x8 bk[4];
#pragma unroll
      for (int j = 0; j < 4; ++j)
        bk[j] = *(const bf16x8*)&Ks[cur][j * 16 + c][swz(c, ks * 32 + g * 8)];
      __builtin_amdgcn_s_setprio(1);
#pragma unroll
      for (int j = 0; j < 4; ++j)
        sv[j] = __builtin_amdgcn_mfma_f32_16x16x32_bf16(bk[j], aq[ks], sv[j], 0, 0, 0);
      __builtin_amdgcn_s_setprio(0);
    }
    // ---- mask + raw v_exp (2^x, LOG2E pre-folded) + lane-local rowsum + P->LDS ----
    {
      const u64 mb = mbits[((size_t)b * S + q0 + c) * MW + t];
      const unsigned mlo = (unsigned)mb, mhi = (unsigned)(mb >> 32);
      f32x4 acc4 = {0.f, 0.f, 0.f, 0.f};
#pragma unroll
      for (int j = 0; j < 4; ++j) {
        const unsigned word = (j < 2) ? mlo : mhi;
        const unsigned sub = word >> (((j & 1) << 4) + (g << 2));
        bf16x4 pk;
#pragma unroll
        for (int r = 0; r < 4; ++r) {
          float e = __builtin_amdgcn_exp2f(sv[j][r]);  // single v_exp_f32
          if ((sub >> r) & 1u) e = 0.f;
          pk[r] = (bf16)e;
          acc4[r] += e;
        }
        *(bf16x4*)&P[w][c][(j * 16 + g * 4) ^ ((c & 7) << 3)] = pk;
      }
      lsum += (acc4[0] + acc4[1]) + (acc4[2] + acc4[3]);
    }
    __threadfence_block();
    // ---- PV: O[q=g*4+r][d=j*16+c] ----
#pragma unroll
    for (int ks = 0; ks < 2; ++ks) {
      const bf16x8 pa = *(const bf16x8*)&P[w][c][(ks * 32 + g * 8) ^ ((c & 7) << 3)];
      bf16x8 bv[4];
#pragma unroll
      for (int j = 0; j < 4; ++j)
        bv[j] = *(const bf16x8*)&Vs[cur][j * 16 + c][swz(c, ks * 32 + g * 8)];
      __builtin_amdgcn_s_setprio(1);
#pragma unroll
      for (int j = 0; j < 4; ++j)
        o[j] = __builtin_amdgcn_mfma_f32_16x16x32_bf16(pa, bv[j], o[j], 0, 0, 0);
      __builtin_amdgcn_s_setprio(0);
    }
    __syncthreads();
  }
  // deferred cross-lane reduction (sum over the 4 g-lanes of each q-row)
  lsum += __shfl_xor(lsum, 16);
  lsum += __shfl_xor(lsum, 32);
#pragma unroll
  for (int r = 0; r < 4; ++r) {
    const float denom = __shfl(lsum, g * 4 + r);
    const float inv = 1.0f / denom;
    const int qrow = q0 + g * 4 + r;
#pragma unroll
    for (int j = 0; j < 4; ++j)
      ctx[((size_t)qrow * B + b) * H + h * HD + j * 16 + c] = (bf16)(o[j][r] * inv);
  }
}

extern "C" void kernel_launch(void* const* d_in, const int* in_sizes, int n_in,
                              void* d_out, int out_size, void* d_ws, size_t ws_size,
                              hipStream_t stream) {
  const float* x = (const float*)d_in[0];
  const void* mask = d_in[1];
  const float* ln_scale = (const float*)d_in[2];
  const float* ln_bias = (const float*)d_in[3];
  const float* w_qkv = (const float*)d_in[4];
  const float* w_out = (const float*)d_in[5];
  float* out = (float*)d_out;

  char* ws = (char*)d_ws;
  size_t off = 0;
  u64* mbits = (u64*)(ws + off); off += (size_t)B * S * (S / 8);      // 1 MB
  bf16* lnb   = (bf16*)(ws + off); off += (size_t)ROWS * H * 2;       // 8 MB
  bf16* wqkvt = (bf16*)(ws + off); off += (size_t)NQKV * H * 2;       // 6 MB
  bf16* woutt = (bf16*)(ws + off); off += (size_t)H * H * 2;          // 2 MB
  bf16* Qb    = (bf16*)(ws + off); off += (size_t)B * NH * S * HD * 2;
  bf16* Kb    = (bf16*)(ws + off); off += (size_t)B * NH * S * HD * 2;
  bf16* Vt    = (bf16*)(ws + off); off += (size_t)B * NH * S * HD * 2;
  bf16* ctx   = (bf16*)(ws + off); off += (size_t)ROWS * H * 2;

  prep_kernel<<<8192 + PACK_WG, 256, 0, stream>>>(w_qkv, w_out, wqkvt, woutt, x, ln_scale, ln_bias, lnb,
                                                  mask, mbits);
  gemm128<0><<<G0_WG, 256, 0, stream>>>(lnb, wqkvt, Qb, Kb, Vt, nullptr);
  attn_kernel<<<dim3(S / 128, B * NH), 512, 0, stream>>>(Qb, Kb, Vt, mbits, ctx);
  gemm128<1><<<dim3(H / 128, ROWS / 128), 256, 0, stream>>>(ctx, woutt, nullptr, nullptr, nullptr, out);
}

// Round 22
// 141.043 us; speedup vs baseline: 1.1307x; 1.1307x over previous
//
#include <hip/hip_runtime.h>

typedef __bf16 bf16;
typedef __attribute__((ext_vector_type(8))) __bf16 bf16x8;
typedef __attribute__((ext_vector_type(4))) __bf16 bf16x4;
typedef __attribute__((ext_vector_type(4))) float f32x4;
typedef unsigned long long u64;

static constexpr int S = 2048, B = 2, H = 1024, NH = 16, HD = 64;
static constexpr int ROWS = S * B;        // 4096 GEMM rows (s*B+b)
static constexpr int NQKV = 3 * NH * HD;  // 3072
static constexpr int KBLK = 64;
static constexpr int NT = S / KBLK;       // 32 k-tiles
static constexpr int MW = S / 64;         // mask u64 words per row
static constexpr float LOG2E = 1.4426950408889634f;
static constexpr int G0_WG = (NQKV / 128) * (ROWS / 128);  // 768 gemm0 work blocks
static constexpr int PACK_WG = (B * S * S) / (256 * 16);   // 2048 pack blocks

__device__ __forceinline__ int swz(int row, int col) { return col ^ ((row & 7) << 3); }

__device__ __forceinline__ void g2l16(const bf16* g, bf16* l) {
  __builtin_amdgcn_global_load_lds((const __attribute__((address_space(1))) void*)g,
                                   (__attribute__((address_space(3))) void*)l, 16, 0, 0);
}

// ---------- prep: weight transpose+cvt (LOG2E in Q cols) + LayerNorm + mask pack ----------
__global__ __launch_bounds__(256) void prep_kernel(const float* __restrict__ wqkv,
                                                   const float* __restrict__ wout,
                                                   bf16* __restrict__ dqkv,
                                                   bf16* __restrict__ dout,
                                                   const float* __restrict__ x,
                                                   const float* __restrict__ sc,
                                                   const float* __restrict__ bi,
                                                   bf16* __restrict__ lnout,
                                                   const void* __restrict__ mask,
                                                   u64* __restrict__ bits) {
  __shared__ float shmem[32 * 33];
  const int bid = blockIdx.x;
  const int tid = threadIdx.x;
  if (bid < 4096) {
    const int bx = bid & 127, by = bid >> 7;
    const bool second = bx >= (NQKV / 32);
    const float* src = second ? wout : wqkv;
    bf16* dst = second ? dout : dqkv;
    const int C = second ? H : NQKV;
    const int c0 = (second ? bx - NQKV / 32 : bx) * 32, r0 = by * 32;
    const int xx = tid & 31, yy = tid >> 5;
#pragma unroll
    for (int i = 0; i < 32; i += 8)
      shmem[(yy + i) * 33 + xx] = src[(size_t)(r0 + yy + i) * C + c0 + xx];
    __syncthreads();
#pragma unroll
    for (int i = 0; i < 32; i += 8) {
      const int col = c0 + yy + i;
      const float scale = (!second && col < 1024) ? LOG2E : 1.0f;
      dst[(size_t)col * H + r0 + xx] = (bf16)(shmem[xx * 33 + yy + i] * scale);
    }
  } else if (bid < 8192) {
    const int row = bid - 4096;
    const float4 v = *(const float4*)&x[(size_t)row * H + tid * 4];
    float s = v.x + v.y + v.z + v.w;
#pragma unroll
    for (int m = 1; m < 64; m <<= 1) s += __shfl_xor(s, m);
    float* red1 = shmem;
    float* red2 = shmem + 8;
    const int w = tid >> 6, lane = tid & 63;
    if (lane == 0) red1[w] = s;
    __syncthreads();
    const float mean = (red1[0] + red1[1] + red1[2] + red1[3]) * (1.0f / H);
    const float dx = v.x - mean, dy = v.y - mean, dz = v.z - mean, dw = v.w - mean;
    float q = dx * dx + dy * dy + dz * dz + dw * dw;
#pragma unroll
    for (int m = 1; m < 64; m <<= 1) q += __shfl_xor(q, m);
    if (lane == 0) red2[w] = q;
    __syncthreads();
    const float var = (red2[0] + red2[1] + red2[2] + red2[3]) * (1.0f / H);
    const float inv = rsqrtf(var + 1e-6f);
    const float4 s4 = *(const float4*)&sc[tid * 4];
    const float4 b4 = *(const float4*)&bi[tid * 4];
    bf16x4 o;
    o[0] = (bf16)(dx * inv * s4.x + b4.x);
    o[1] = (bf16)(dy * inv * s4.y + b4.y);
    o[2] = (bf16)(dz * inv * s4.z + b4.z);
    o[3] = (bf16)(dw * inv * s4.w + b4.w);
    *(bf16x4*)&lnout[(size_t)row * H + tid * 4] = o;
  } else {
    // ---- mask pack, 4096 elements per block; dtype detected from OWN 4KB byte window ----
    const int p = bid - 8192;
    const size_t base = (size_t)p * 4096;
    int* det = (int*)shmem;
    if (tid == 0) det[0] = 0;
    __syncthreads();
    const uint4 wv = *(const uint4*)((const unsigned char*)mask + base + (size_t)tid * 16);
    const unsigned any3 = (wv.x | wv.y | wv.z | wv.w) & 0xFFFFFF00u;
    if (any3) atomicOr(det, 1);
    __syncthreads();
    const bool imode = (det[0] == 0);
#pragma unroll
    for (int k = 0; k < 16; ++k) {
      const size_t e = base + k * 256 + tid;
      int mv;
      if (imode) mv = ((const int*)mask)[e];
      else mv = (int)((const unsigned char*)mask)[e];
      const u64 bal = __ballot(mv != 0);
      if ((tid & 63) == 0) bits[e >> 6] = bal;
    }
  }
}

// ---------- 128x128 bf16 MFMA GEMM, dbuf + COUNTED-vmcnt pipeline (T4), src-swizzled LDS ----------
template <int EPI>
__global__ __launch_bounds__(256) void gemm128(const bf16* __restrict__ A, const bf16* __restrict__ Bt,
                                               bf16* __restrict__ qo, bf16* __restrict__ ko,
                                               bf16* __restrict__ vo, float* __restrict__ out) {
  constexpr int K = 1024;
  constexpr int NKT = K / 64;
  __shared__ __align__(16) bf16 As[2][128][64];
  __shared__ __align__(16) bf16 Bs[2][128][64];
  int lin, NX, total;
  if (EPI == 0) {
    lin = blockIdx.x;
    NX = NQKV / 128; total = G0_WG;
  } else {
    lin = blockIdx.y * gridDim.x + blockIdx.x;
    NX = gridDim.x; total = gridDim.x * gridDim.y;
  }
  const int cpx = total >> 3;
  const int work = (lin & 7) * cpx + (lin >> 3);
  const int bm = (work / NX) * 128, bn = (work % NX) * 128;
  const bool isV = (EPI == 0) && (bn >= 2048);
  const int tid = threadIdx.x;
  const int wave = tid >> 6, lane = tid & 63;
  const int wm = (wave >> 1) * 64, wn = (wave & 1) * 64;
  const int g = lane >> 4, l15 = lane & 15;
  const int lr = lane >> 3;
  const int lc = 8 * ((lane & 7) ^ lr);
  const bf16* Ab = &A[(size_t)bm * K];
  const bf16* Bb = &Bt[(size_t)bn * K];

  f32x4 acc[4][4] = {};
  // prologue: issue prefetch of tile 0 into buf 0 (stays in flight into the loop)
#pragma unroll
  for (int p = 0; p < 4; ++p) {
    const int r0 = wave * 32 + p * 8;
    g2l16(&Ab[(size_t)(r0 + lr) * K + lc], &As[0][r0][0]);
    g2l16(&Bb[(size_t)(r0 + lr) * K + lc], &Bs[0][r0][0]);
  }

  for (int kt = 0; kt < NKT; ++kt) {
    const int cur = kt & 1;
    if (kt + 1 < NKT) {
      const int ko2 = (kt + 1) * 64;
#pragma unroll
      for (int p = 0; p < 4; ++p) {
        const int r0 = wave * 32 + p * 8;
        g2l16(&Ab[(size_t)(r0 + lr) * K + ko2 + lc], &As[cur ^ 1][r0][0]);
        g2l16(&Bb[(size_t)(r0 + lr) * K + ko2 + lc], &Bs[cur ^ 1][r0][0]);
      }
      // wait for tile-kt fill only; the 8 loads for kt+1 remain outstanding
      asm volatile("s_waitcnt vmcnt(8)" ::: "memory");
    } else {
      asm volatile("s_waitcnt vmcnt(0)" ::: "memory");
    }
    __builtin_amdgcn_sched_barrier(0);
    __builtin_amdgcn_s_barrier();  // all waves: buf[cur] ready
    __builtin_amdgcn_sched_barrier(0);
#pragma unroll
    for (int ks = 0; ks < 2; ++ks) {
      bf16x8 af[4], bb[4];
#pragma unroll
      for (int i = 0; i < 4; ++i) af[i] = *(const bf16x8*)&As[cur][wm + i * 16 + l15][swz(l15, ks * 32 + g * 8)];
#pragma unroll
      for (int j = 0; j < 4; ++j) bb[j] = *(const bf16x8*)&Bs[cur][wn + j * 16 + l15][swz(l15, ks * 32 + g * 8)];
      __builtin_amdgcn_s_setprio(1);
      if (isV) {
#pragma unroll
        for (int i = 0; i < 4; ++i)
#pragma unroll
          for (int j = 0; j < 4; ++j)
            acc[i][j] = __builtin_amdgcn_mfma_f32_16x16x32_bf16(bb[j], af[i], acc[i][j], 0, 0, 0);
      } else {
#pragma unroll
        for (int i = 0; i < 4; ++i)
#pragma unroll
          for (int j = 0; j < 4; ++j)
            acc[i][j] = __builtin_amdgcn_mfma_f32_16x16x32_bf16(af[i], bb[j], acc[i][j], 0, 0, 0);
      }
      __builtin_amdgcn_s_setprio(0);
    }
    __builtin_amdgcn_sched_barrier(0);
    asm volatile("s_waitcnt lgkmcnt(0)" ::: "memory");  // my reads of buf[cur] retired
    __builtin_amdgcn_sched_barrier(0);
    __builtin_amdgcn_s_barrier();  // all waves done with buf[cur] -> safe to overwrite next iter
    __builtin_amdgcn_sched_barrier(0);
  }
#pragma unroll
  for (int i = 0; i < 4; ++i) {
#pragma unroll
    for (int j = 0; j < 4; ++j) {
#pragma unroll
      for (int r = 0; r < 4; ++r) {
        const float val = acc[i][j][r];
        if (isV) {
          const int row = bm + wm + i * 16 + l15;
          const int col = bn + wn + j * 16 + g * 4 + r;
          const int f = col & 1023;
          const int h = f >> 6, d = f & 63;
          const int sdx = row >> 1, b = row & 1;
          vo[(((size_t)b * NH + h) * HD + d) * S + sdx] = (bf16)val;
        } else if (EPI == 0) {
          const int row = bm + wm + i * 16 + g * 4 + r;
          const int col = bn + wn + j * 16 + l15;
          const int kk = col >> 10, f = col & 1023;
          const int h = f >> 6, d = f & 63;
          const int sdx = row >> 1, b = row & 1;
          const size_t head = (size_t)b * NH + h;
          if (kk == 0)
            qo[(head * S + sdx) * HD + d] = (bf16)val;
          else
            ko[(head * S + sdx) * HD + d] = (bf16)val;
        } else {
          const int row = bm + wm + i * 16 + g * 4 + r;
          const int col = bn + wn + j * 16 + l15;
          out[(size_t)row * H + col] = val;
        }
      }
    }
  }
}

// ---------- flash attention: 8 waves x 16 q-rows (128/block), grid 512, swapped QK^T ----------
__global__ __launch_bounds__(512, 4) void attn_kernel(const bf16* __restrict__ Qb, const bf16* __restrict__ Kb,
                                                      const bf16* __restrict__ Vt, const u64* __restrict__ mbits,
                                                      bf16* __restrict__ ctx) {
  __shared__ __align__(16) bf16 Ks[2][64][64];
  __shared__ __align__(16) bf16 Vs[2][64][64];
  __shared__ __align__(16) bf16 P[8][16][64];
  // XCD-chunked swizzle: 512 blocks -> each XCD gets 64 consecutive works (4 heads)
  const int lin = blockIdx.y * 16 + blockIdx.x;
  const int work = ((lin & 7) << 6) | (lin >> 3);
  const int bh = work >> 4, qb = work & 15;
  const int b = bh >> 4, h = bh & 15;
  const int tid = threadIdx.x, w = tid >> 6, lane = tid & 63;
  const int g = lane >> 4, c = lane & 15;
  const int q0 = qb * 128 + w * 16;
  const size_t head = (size_t)b * NH + h;
  const bf16* Qh = Qb + head * S * HD;
  const bf16* Kh = Kb + head * S * HD;
  const bf16* Vh = Vt + head * HD * S;

  // staging: wave w stages rows [w*8, w*8+8); LDS linear, swizzle on global source col
  const int srow = w * 8 + (lane >> 3);
  const int scol = 8 * ((lane & 7) ^ (lane >> 3));

  bf16x8 aq[2];
#pragma unroll
  for (int ks = 0; ks < 2; ++ks)
    aq[ks] = *(const bf16x8*)&Qh[(size_t)(q0 + c) * HD + ks * 32 + g * 8];

  f32x4 o[4] = {};
  float lsum = 0.f;  // lane-local partial; cross-lane reduction deferred to epilogue

  // prologue: stage tile 0 into buf0
  g2l16(&Kh[(size_t)srow * HD + scol], &Ks[0][w * 8][0]);
  g2l16(&Vh[(size_t)srow * S + scol], &Vs[0][w * 8][0]);
  __syncthreads();

  for (int t = 0; t < NT; ++t) {
    const int cur = t & 1;
    if (t + 1 < NT) {  // async staging for tile t+1 (drained at end-of-iter barrier)
      const int kt1 = (t + 1) * KBLK;
      g2l16(&Kh[(size_t)(kt1 + srow) * HD + scol], &Ks[cur ^ 1][w * 8][0]);
      g2l16(&Vh[(size_t)srow * S + kt1 + scol], &Vs[cur ^ 1][w * 8][0]);
    }
    // ---- QK^T swapped: sv[j][r] = log2e * S[q=q0+c][k=kt+j*16+g*4+r] ----
    f32x4 sv[4] = {};
#pragma unroll
    for (int ks = 0; ks < 2; ++ks) {
      bf16x8 bk[4];
#pragma unroll
      for (int j = 0; j < 4; ++j)
        bk[j] = *(const bf16x8*)&Ks[cur][j * 16 + c][swz(c, ks * 32 + g * 8)];
      __builtin_amdgcn_s_setprio(1);
#pragma unroll
      for (int j = 0; j < 4; ++j)
        sv[j] = __builtin_amdgcn_mfma_f32_16x16x32_bf16(bk[j], aq[ks], sv[j], 0, 0, 0);
      __builtin_amdgcn_s_setprio(0);
    }
    // ---- mask + raw v_exp (2^x, LOG2E pre-folded) + lane-local rowsum + P->LDS ----
    {
      const u64 mb = mbits[((size_t)b * S + q0 + c) * MW + t];
      const unsigned mlo = (unsigned)mb, mhi = (unsigned)(mb >> 32);
      f32x4 acc4 = {0.f, 0.f, 0.f, 0.f};
#pragma unroll
      for (int j = 0; j < 4; ++j) {
        const unsigned word = (j < 2) ? mlo : mhi;
        const unsigned sub = word >> (((j & 1) << 4) + (g << 2));
        bf16x4 pk;
#pragma unroll
        for (int r = 0; r < 4; ++r) {
          float e = __builtin_amdgcn_exp2f(sv[j][r]);  // single v_exp_f32
          if ((sub >> r) & 1u) e = 0.f;
          pk[r] = (bf16)e;
          acc4[r] += e;
        }
        *(bf16x4*)&P[w][c][(j * 16 + g * 4) ^ ((c & 7) << 3)] = pk;
      }
      lsum += (acc4[0] + acc4[1]) + (acc4[2] + acc4[3]);
    }
    __threadfence_block();
    // ---- PV: O[q=g*4+r][d=j*16+c] ----
#pragma unroll
    for (int ks = 0; ks < 2; ++ks) {
      const bf16x8 pa = *(const bf16x8*)&P[w][c][(ks * 32 + g * 8) ^ ((c & 7) << 3)];
      bf16x8 bv[4];
#pragma unroll
      for (int j = 0; j < 4; ++j)
        bv[j] = *(const bf16x8*)&Vs[cur][j * 16 + c][swz(c, ks * 32 + g * 8)];
      __builtin_amdgcn_s_setprio(1);
#pragma unroll
      for (int j = 0; j < 4; ++j)
        o[j] = __builtin_amdgcn_mfma_f32_16x16x32_bf16(pa, bv[j], o[j], 0, 0, 0);
      __builtin_amdgcn_s_setprio(0);
    }
    __syncthreads();
  }
  // deferred cross-lane reduction (sum over the 4 g-lanes of each q-row)
  lsum += __shfl_xor(lsum, 16);
  lsum += __shfl_xor(lsum, 32);
#pragma unroll
  for (int r = 0; r < 4; ++r) {
    const float denom = __shfl(lsum, g * 4 + r);
    const float inv = 1.0f / denom;
    const int qrow = q0 + g * 4 + r;
#pragma unroll
    for (int j = 0; j < 4; ++j)
      ctx[((size_t)qrow * B + b) * H + h * HD + j * 16 + c] = (bf16)(o[j][r] * inv);
  }
}

extern "C" void kernel_launch(void* const* d_in, const int* in_sizes, int n_in,
                              void* d_out, int out_size, void* d_ws, size_t ws_size,
                              hipStream_t stream) {
  const float* x = (const float*)d_in[0];
  const void* mask = d_in[1];
  const float* ln_scale = (const float*)d_in[2];
  const float* ln_bias = (const float*)d_in[3];
  const float* w_qkv = (const float*)d_in[4];
  const float* w_out = (const float*)d_in[5];
  float* out = (float*)d_out;

  char* ws = (char*)d_ws;
  size_t off = 0;
  u64* mbits = (u64*)(ws + off); off += (size_t)B * S * (S / 8);      // 1 MB
  bf16* lnb   = (bf16*)(ws + off); off += (size_t)ROWS * H * 2;       // 8 MB
  bf16* wqkvt = (bf16*)(ws + off); off += (size_t)NQKV * H * 2;       // 6 MB
  bf16* woutt = (bf16*)(ws + off); off += (size_t)H * H * 2;          // 2 MB
  bf16* Qb    = (bf16*)(ws + off); off += (size_t)B * NH * S * HD * 2;
  bf16* Kb    = (bf16*)(ws + off); off += (size_t)B * NH * S * HD * 2;
  bf16* Vt    = (bf16*)(ws + off); off += (size_t)B * NH * S * HD * 2;
  bf16* ctx   = (bf16*)(ws + off); off += (size_t)ROWS * H * 2;

  prep_kernel<<<8192 + PACK_WG, 256, 0, stream>>>(w_qkv, w_out, wqkvt, woutt, x, ln_scale, ln_bias, lnb,
                                                  mask, mbits);
  gemm128<0><<<G0_WG, 256, 0, stream>>>(lnb, wqkvt, Qb, Kb, Vt, nullptr);
  attn_kernel<<<dim3(S / 128, B * NH), 512, 0, stream>>>(Qb, Kb, Vt, mbits, ctx);
  gemm128<1><<<dim3(H / 128, ROWS / 128), 256, 0, stream>>>(ctx, woutt, nullptr, nullptr, nullptr, out);
}